// Round 5
// baseline (231.143 us; speedup 1.0000x reference)
//
#include <hip/hip_runtime.h>

typedef __bf16 bf16;
typedef __bf16 bf16x8 __attribute__((ext_vector_type(8)));
typedef __bf16 bf16x4 __attribute__((ext_vector_type(4)));
typedef float f32x4 __attribute__((ext_vector_type(4)));

// x: [256][4096] f32, conv_w: [1536][256] f32, out: [512][4096] f32
// heads=8; channels per head: key [0:64), query [64:128), value [128:192)
// qkvT per head (786432): [QT(query) [4096][64] | KT(key) [4096][64] | V [64][4096]]
// k_conv stores RAW (pre-norm) bf16; k_normqk applies affine to Q/K in place
// (query gets log2(e)/8 folded); V's affine folds exactly into k_final.

#define QF 0.18033688011112042f   // log2(e)/8

// ---------------- K_misc: xpose + cast_w + zero(cs) ----------------
__global__ void k_misc(const float* __restrict__ x, const float* __restrict__ w,
                       bf16* __restrict__ xT, bf16* __restrict__ wb, float* __restrict__ cs) {
    int b = blockIdx.x;
    if (b < 512) {
        int t = b * 256 + threadIdx.x;
        int p  = t & 4095;
        int c0 = (t >> 12) * 8;
        bf16x8 o;
#pragma unroll
        for (int j = 0; j < 8; j++) o[j] = (bf16)x[(c0 + j) * 4096 + p];
        *(bf16x8*)(xT + p * 256 + c0) = o;
    } else if (b < 896) {
        int idx = ((b - 512) * 256 + threadIdx.x) * 4;
        float4 f = *(const float4*)(w + idx);
        bf16x4 o;
        o[0] = (bf16)f.x; o[1] = (bf16)f.y; o[2] = (bf16)f.z; o[3] = (bf16)f.w;
        *(bf16x4*)(wb + idx) = o;
    } else {
#pragma unroll
        for (int i = 0; i < 12; i++) cs[i * 256 + threadIdx.x] = 0.f;
    }
}

// ---------------- K1: conv GEMM -> stats + LDS-transposed coalesced stores ----------------
__global__ __launch_bounds__(256) void k_conv(const bf16* __restrict__ Wb,
                                              const bf16* __restrict__ xT,
                                              bf16* __restrict__ qkvT,
                                              float* __restrict__ cs) {
    __shared__ __attribute__((aligned(16))) bf16 tile[64 * 72];
    int wid = threadIdx.x >> 6, lane = threadIdx.x & 63;
    int quad = lane >> 4, l15 = lane & 15;
    int g  = blockIdx.x % 24;
    int pb = (blockIdx.x / 24) * 64;
    int h = g / 3, sec = g % 3;          // 0=key 1=query 2=value
    int ob = g * 64;
    int orow = ob + wid * 16 + l15;

    f32x4 acc[4];
#pragma unroll
    for (int c = 0; c < 4; c++) acc[c] = (f32x4){0.f, 0.f, 0.f, 0.f};

#pragma unroll
    for (int ks = 0; ks < 8; ks++) {
        bf16x8 a = *(const bf16x8*)(Wb + orow * 256 + ks * 32 + quad * 8);
#pragma unroll
        for (int c = 0; c < 4; c++) {
            bf16x8 b = *(const bf16x8*)(xT + (pb + c * 16 + l15) * 256 + ks * 32 + quad * 8);
            acc[c] = __builtin_amdgcn_mfma_f32_16x16x32_bf16(a, b, acc[c], 0, 0, 0);
        }
    }

    int ch0 = wid * 16 + quad * 4;
#pragma unroll
    for (int r = 0; r < 4; r++) {
        float sp  = acc[0][r] + acc[1][r] + acc[2][r] + acc[3][r];
        float ssp = acc[0][r] * acc[0][r] + acc[1][r] * acc[1][r]
                  + acc[2][r] * acc[2][r] + acc[3][r] * acc[3][r];
#pragma unroll
        for (int m = 1; m < 16; m <<= 1) {
            sp  += __shfl_xor(sp,  m, 64);
            ssp += __shfl_xor(ssp, m, 64);
        }
        if (l15 == 0) {
            atomicAdd(cs + (ob + ch0 + r) * 2,     sp);
            atomicAdd(cs + (ob + ch0 + r) * 2 + 1, ssp);
        }
    }

    if (sec == 2) {                      // V wants [ch][px]
#pragma unroll
        for (int c = 0; c < 4; c++)
#pragma unroll
            for (int r = 0; r < 4; r++)
                tile[(ch0 + r) * 72 + c * 16 + l15] = (bf16)acc[c][r];
    } else {                             // Q/K want [px][ch]
#pragma unroll
        for (int c = 0; c < 4; c++) {
            bf16x4 o;
#pragma unroll
            for (int r = 0; r < 4; r++) o[r] = (bf16)acc[c][r];
            *(bf16x4*)(&tile[(c * 16 + l15) * 72 + ch0]) = o;
        }
    }
    __syncthreads();
    bf16* base = qkvT + h * 786432;
    int t = threadIdx.x;
    if (sec == 2) {
        bf16* V = base + 524288;
#pragma unroll
        for (int it = 0; it < 2; it++) {
            int e = it * 256 + t; int ch = e >> 3; int pxo = (e & 7) * 8;
            *(bf16x8*)(V + ch * 4096 + pb + pxo) = *(const bf16x8*)(&tile[ch * 72 + pxo]);
        }
    } else {
        bf16* dst = base + (sec == 0 ? 262144 : 0);
#pragma unroll
        for (int it = 0; it < 2; it++) {
            int e = it * 256 + t; int px = e >> 3; int cho = (e & 7) * 8;
            *(bf16x8*)(dst + (pb + px) * 64 + cho) = *(const bf16x8*)(&tile[px * 72 + cho]);
        }
    }
}

// ---------------- K2: in-place affine on Q/K (group stats computed inline) ----------------
__global__ __launch_bounds__(256) void k_normqk(bf16* __restrict__ qkv,
                                                const float2* __restrict__ cs,
                                                const float* __restrict__ gnw,
                                                const float* __restrict__ gnb) {
    int h    = blockIdx.x >> 8;
    int base = (blockIdx.x & 255) * 2048;            // 2048 elems per WG, section-pure
    int isQ  = base < 262144;
    int g    = h * 3 + (isQ ? 1 : 0);

    // redundant per-wave 64-lane reduction of the group's channel stats
    int c = threadIdx.x & 63;
    float2 v = cs[g * 64 + c];
    float s = v.x, ss = v.y;
#pragma unroll
    for (int m = 1; m < 64; m <<= 1) { s += __shfl_xor(s, m, 64); ss += __shfl_xor(ss, m, 64); }
    const float N = 64.0f * 4096.0f;
    float mean = s / N;
    float inv  = rsqrtf(ss / N - mean * mean + 1e-5f);
    float f = isQ ? QF : 1.0f;

    int t = threadIdx.x;
    int e = base + t * 8;
    int gc = h * 192 + (isQ ? 64 : 0) + (e & 63);    // 8 consecutive channels
    bf16* p = qkv + h * 786432 + e;
    bf16x8 vv = *(bf16x8*)p;
    bf16x8 o;
#pragma unroll
    for (int j = 0; j < 8; j++) {
        float gw = gnw[gc + j];
        float a = inv * gw * f;
        float b = (gnb[gc + j] - mean * inv * gw) * f;
        o[j] = (bf16)(a * (float)vv[j] + b);
    }
    *(bf16x8*)p = o;
}

// ---------------- K3: flash attention — NO barriers, fragments from L1/L2 ----------------
// grid 768 = 8 heads x 32 q-blocks(128q) x 3 L-splits; wave owns 32 q.
__global__ __launch_bounds__(256, 3) void k_attn(const bf16* __restrict__ qkvT,
                                                 bf16* __restrict__ Opart,
                                                 float* __restrict__ Lsum) {
    int bid   = blockIdx.x;
    int h     = bid & 7;                  // XCD L2 affinity
    int qb    = (bid >> 3) & 31;
    int split = bid >> 8;                 // 0..2
    int wid = threadIdx.x >> 6, lane = threadIdx.x & 63;
    int quad = lane >> 4, l15 = lane & 15;
    const bf16* QT = qkvT + h * 786432;
    const bf16* KT = QT + 262144;
    const bf16* V  = QT + 524288;
    int qw = qb * 128 + wid * 32;         // wave's 32 q

    __shared__ __attribute__((aligned(16))) bf16 Ps[4][32 * 72];   // per-wave private

    // Q B-fragments (loop-invariant)
    bf16x8 bq[2][2];
#pragma unroll
    for (int qs = 0; qs < 2; qs++)
#pragma unroll
        for (int ks = 0; ks < 2; ks++)
            bq[qs][ks] = *(const bf16x8*)(QT + (qw + qs * 16 + l15) * 64 + ks * 32 + quad * 8);

    f32x4 oacc[4][2];
#pragma unroll
    for (int c = 0; c < 4; c++)
#pragma unroll
        for (int qs = 0; qs < 2; qs++) oacc[c][qs] = (f32x4){0.f, 0.f, 0.f, 0.f};
    float ls[2] = {0.f, 0.f};

    int t0 = (split * 64) / 3, t1 = ((split + 1) * 64) / 3;
    for (int lt = t0; lt < t1; lt++) {
        int lbase = lt * 64;

        // K fragments straight from global (L1-served within the WG)
        bf16x8 ak[2][4];
#pragma unroll
        for (int ks = 0; ks < 2; ks++)
#pragma unroll
            for (int lb = 0; lb < 4; lb++)
                ak[ks][lb] = *(const bf16x8*)(KT + (lbase + lb * 16 + l15) * 64 + ks * 32 + quad * 8);
        // V fragments straight from global
        bf16x8 av[2][4];
#pragma unroll
        for (int ks = 0; ks < 2; ks++)
#pragma unroll
            for (int c = 0; c < 4; c++)
                av[ks][c] = *(const bf16x8*)(V + (c * 16 + l15) * 4096 + lbase + ks * 32 + quad * 8);

        // S^T = K·Q -> P = exp2 -> Ps (per-wave, no barrier)
#pragma unroll
        for (int qs = 0; qs < 2; qs++) {
            f32x4 s[4];
#pragma unroll
            for (int lb = 0; lb < 4; lb++) s[lb] = (f32x4){0.f, 0.f, 0.f, 0.f};
#pragma unroll
            for (int ks = 0; ks < 2; ks++)
#pragma unroll
                for (int lb = 0; lb < 4; lb++)
                    s[lb] = __builtin_amdgcn_mfma_f32_16x16x32_bf16(ak[ks][lb], bq[qs][ks], s[lb], 0, 0, 0);
#pragma unroll
            for (int lb = 0; lb < 4; lb++) {
                float p0 = exp2f(s[lb][0]);
                float p1 = exp2f(s[lb][1]);
                float p2 = exp2f(s[lb][2]);
                float p3 = exp2f(s[lb][3]);
                ls[qs] += (p0 + p1) + (p2 + p3);
                bf16x4 pk;
                pk[0] = (bf16)p0; pk[1] = (bf16)p1; pk[2] = (bf16)p2; pk[3] = (bf16)p3;
                *(bf16x4*)(&Ps[wid][(qs * 16 + l15) * 72 + lb * 16 + quad * 4]) = pk;
            }
        }

        // O += V·P
#pragma unroll
        for (int qs = 0; qs < 2; qs++) {
            bf16x8 bp0 = *(const bf16x8*)(&Ps[wid][(qs * 16 + l15) * 72 + quad * 8]);
            bf16x8 bp1 = *(const bf16x8*)(&Ps[wid][(qs * 16 + l15) * 72 + 32 + quad * 8]);
#pragma unroll
            for (int c = 0; c < 4; c++) {
                oacc[c][qs] = __builtin_amdgcn_mfma_f32_16x16x32_bf16(av[0][c], bp0, oacc[c][qs], 0, 0, 0);
                oacc[c][qs] = __builtin_amdgcn_mfma_f32_16x16x32_bf16(av[1][c], bp1, oacc[c][qs], 0, 0, 0);
            }
        }
    }

#pragma unroll
    for (int qs = 0; qs < 2; qs++) {
        float l = ls[qs];
        l += __shfl_xor(l, 16, 64);
        l += __shfl_xor(l, 32, 64);
        if (quad == 0)
            Lsum[split * 32768 + h * 4096 + qw + qs * 16 + l15] = l;
    }

    bf16* Ob = Opart + split * 2097152;
#pragma unroll
    for (int c = 0; c < 4; c++)
#pragma unroll
        for (int qs = 0; qs < 2; qs++)
#pragma unroll
            for (int r = 0; r < 4; r++)
                Ob[(h * 64 + c * 16 + quad * 4 + r) * 4096 + qw + qs * 16 + l15] = (bf16)oacc[c][qs][r];
}

// ---------------- K4: combine 3 splits + V affine (stats inline) + normalize ----------------
__global__ void k_final(const bf16* __restrict__ Opart, const float* __restrict__ Lsum,
                        const float2* __restrict__ cs, const float* __restrict__ gnw,
                        const float* __restrict__ gnb, float* __restrict__ out) {
    int gid = blockIdx.x * 256 + threadIdx.x;    // 262144
    int row = gid >> 9;                          // WG-uniform (512 gids per row)
    int c8  = (gid & 511) << 3;
    int h   = row >> 6;

    // inline V-group stats (redundant per-wave reduction)
    int g = h * 3 + 2;
    int c = threadIdx.x & 63;
    float2 v = cs[g * 64 + c];
    float s = v.x, ss = v.y;
#pragma unroll
    for (int m = 1; m < 64; m <<= 1) { s += __shfl_xor(s, m, 64); ss += __shfl_xor(ss, m, 64); }
    const float N = 64.0f * 4096.0f;
    float mean = s / N;
    float inv  = rsqrtf(ss / N - mean * mean + 1e-5f);
    int gi = h * 192 + 128 + (row & 63);
    float gw = gnw[gi];
    float va = inv * gw;
    float vb = gnb[gi] - mean * inv * gw;

    float o[8] = {0, 0, 0, 0, 0, 0, 0, 0};
    float l[8] = {0, 0, 0, 0, 0, 0, 0, 0};
#pragma unroll
    for (int sp = 0; sp < 3; sp++) {
        bf16x8 vv = *(const bf16x8*)(Opart + sp * 2097152 + row * 4096 + c8);
        const float* L = Lsum + sp * 32768 + h * 4096 + c8;
        float4 l0 = *(const float4*)L;
        float4 l1 = *(const float4*)(L + 4);
#pragma unroll
        for (int j = 0; j < 8; j++) o[j] += (float)vv[j];
        l[0] += l0.x; l[1] += l0.y; l[2] += l0.z; l[3] += l0.w;
        l[4] += l1.x; l[5] += l1.y; l[6] += l1.z; l[7] += l1.w;
    }
    float4 r0, r1;
    r0.x = va * o[0] / l[0] + vb; r0.y = va * o[1] / l[1] + vb;
    r0.z = va * o[2] / l[2] + vb; r0.w = va * o[3] / l[3] + vb;
    r1.x = va * o[4] / l[4] + vb; r1.y = va * o[5] / l[5] + vb;
    r1.z = va * o[6] / l[6] + vb; r1.w = va * o[7] / l[7] + vb;
    *(float4*)(out + row * 4096 + c8)     = r0;
    *(float4*)(out + row * 4096 + c8 + 4) = r1;
}

extern "C" void kernel_launch(void* const* d_in, const int* in_sizes, int n_in,
                              void* d_out, int out_size, void* d_ws, size_t ws_size,
                              hipStream_t stream) {
    const float* x      = (const float*)d_in[0];
    const float* conv_w = (const float*)d_in[1];
    const float* gn_w   = (const float*)d_in[2];
    const float* gn_b   = (const float*)d_in[3];
    float* out = (float*)d_out;
    char* ws = (char*)d_ws;

    // qkvT [0, 12582912); Opart 3x4MB [12582912, 25165824); Wb/xT alias Opart
    // (dead after k_conv, Opart first written by k_attn).
    bf16*   qkvT  = (bf16*) (ws);
    bf16*   Opart = (bf16*) (ws + 12582912);
    bf16*   Wb    = (bf16*) (ws + 12582912);
    bf16*   xT    = (bf16*) (ws + 13369344);
    float*  Lsum  = (float*)(ws + 25165824);        // 3*131072 B
    float*  cs    = (float*)(ws + 25559040);        // 12288 B

    hipLaunchKernelGGL(k_misc,   dim3(897),  dim3(256), 0, stream, x, conv_w, xT, Wb, cs);
    hipLaunchKernelGGL(k_conv,   dim3(1536), dim3(256), 0, stream, Wb, xT, qkvT, cs);
    hipLaunchKernelGGL(k_normqk, dim3(2048), dim3(256), 0, stream, qkvT, (const float2*)cs, gn_w, gn_b);
    hipLaunchKernelGGL(k_attn,   dim3(768),  dim3(256), 0, stream, qkvT, Opart, Lsum);
    hipLaunchKernelGGL(k_final,  dim3(1024), dim3(256), 0, stream, Opart, Lsum, (const float2*)cs, gn_w, gn_b, out);
}

// Round 6
// 149.332 us; speedup vs baseline: 1.5478x; 1.5478x over previous
//
#include <hip/hip_runtime.h>

typedef __bf16 bf16;
typedef __bf16 bf16x8 __attribute__((ext_vector_type(8)));
typedef __bf16 bf16x4 __attribute__((ext_vector_type(4)));
typedef float f32x4 __attribute__((ext_vector_type(4)));

// x: [256][4096] f32, conv_w: [1536][256] f32, out: [512][4096] f32
// heads=8; channels per head: key [0:64), query [64:128), value [128:192)
// qkvT per head (786432): [QT(query) [4096][64] | KT(key) [4096][64] | V [64][4096]]
// k_conv stores RAW (pre-norm) bf16. Q/K GroupNorm affine is applied inside
// k_attn (Q at frag load, K at LDS staging; query gets log2(e)/8 folded).
// V's affine folds exactly into k_final: out = a_v*(sum O)/(sum L) + b_v.

#define QF 0.18033688011112042f   // log2(e)/8

// ---------------- K_misc: xpose + cast_w + zero(cs) ----------------
__global__ void k_misc(const float* __restrict__ x, const float* __restrict__ w,
                       bf16* __restrict__ xT, bf16* __restrict__ wb, float* __restrict__ cs) {
    int b = blockIdx.x;
    if (b < 512) {
        int t = b * 256 + threadIdx.x;
        int p  = t & 4095;
        int c0 = (t >> 12) * 8;
        bf16x8 o;
#pragma unroll
        for (int j = 0; j < 8; j++) o[j] = (bf16)x[(c0 + j) * 4096 + p];
        *(bf16x8*)(xT + p * 256 + c0) = o;
    } else if (b < 896) {
        int idx = ((b - 512) * 256 + threadIdx.x) * 4;
        float4 f = *(const float4*)(w + idx);
        bf16x4 o;
        o[0] = (bf16)f.x; o[1] = (bf16)f.y; o[2] = (bf16)f.z; o[3] = (bf16)f.w;
        *(bf16x4*)(wb + idx) = o;
    } else {
#pragma unroll
        for (int i = 0; i < 12; i++) cs[i * 256 + threadIdx.x] = 0.f;
    }
}

// ---------------- K1: conv GEMM -> stats + LDS-transposed coalesced stores ----------------
__global__ __launch_bounds__(256) void k_conv(const bf16* __restrict__ Wb,
                                              const bf16* __restrict__ xT,
                                              bf16* __restrict__ qkvT,
                                              float* __restrict__ cs) {
    __shared__ __attribute__((aligned(16))) bf16 tile[64 * 72];
    int wid = threadIdx.x >> 6, lane = threadIdx.x & 63;
    int quad = lane >> 4, l15 = lane & 15;
    int g  = blockIdx.x % 24;
    int pb = (blockIdx.x / 24) * 64;
    int h = g / 3, sec = g % 3;          // 0=key 1=query 2=value
    int ob = g * 64;
    int orow = ob + wid * 16 + l15;

    f32x4 acc[4];
#pragma unroll
    for (int c = 0; c < 4; c++) acc[c] = (f32x4){0.f, 0.f, 0.f, 0.f};

#pragma unroll
    for (int ks = 0; ks < 8; ks++) {
        bf16x8 a = *(const bf16x8*)(Wb + orow * 256 + ks * 32 + quad * 8);
#pragma unroll
        for (int c = 0; c < 4; c++) {
            bf16x8 b = *(const bf16x8*)(xT + (pb + c * 16 + l15) * 256 + ks * 32 + quad * 8);
            acc[c] = __builtin_amdgcn_mfma_f32_16x16x32_bf16(a, b, acc[c], 0, 0, 0);
        }
    }

    int ch0 = wid * 16 + quad * 4;
#pragma unroll
    for (int r = 0; r < 4; r++) {
        float sp  = acc[0][r] + acc[1][r] + acc[2][r] + acc[3][r];
        float ssp = acc[0][r] * acc[0][r] + acc[1][r] * acc[1][r]
                  + acc[2][r] * acc[2][r] + acc[3][r] * acc[3][r];
#pragma unroll
        for (int m = 1; m < 16; m <<= 1) {
            sp  += __shfl_xor(sp,  m, 64);
            ssp += __shfl_xor(ssp, m, 64);
        }
        if (l15 == 0) {
            atomicAdd(cs + (ob + ch0 + r) * 2,     sp);
            atomicAdd(cs + (ob + ch0 + r) * 2 + 1, ssp);
        }
    }

    if (sec == 2) {                      // V wants [ch][px]
#pragma unroll
        for (int c = 0; c < 4; c++)
#pragma unroll
            for (int r = 0; r < 4; r++)
                tile[(ch0 + r) * 72 + c * 16 + l15] = (bf16)acc[c][r];
    } else {                             // Q/K want [px][ch]
#pragma unroll
        for (int c = 0; c < 4; c++) {
            bf16x4 o;
#pragma unroll
            for (int r = 0; r < 4; r++) o[r] = (bf16)acc[c][r];
            *(bf16x4*)(&tile[(c * 16 + l15) * 72 + ch0]) = o;
        }
    }
    __syncthreads();
    bf16* base = qkvT + h * 786432;
    int t = threadIdx.x;
    if (sec == 2) {
        bf16* V = base + 524288;
#pragma unroll
        for (int it = 0; it < 2; it++) {
            int e = it * 256 + t; int ch = e >> 3; int pxo = (e & 7) * 8;
            *(bf16x8*)(V + ch * 4096 + pb + pxo) = *(const bf16x8*)(&tile[ch * 72 + pxo]);
        }
    } else {
        bf16* dst = base + (sec == 0 ? 262144 : 0);
#pragma unroll
        for (int it = 0; it < 2; it++) {
            int e = it * 256 + t; int px = e >> 3; int cho = (e & 7) * 8;
            *(bf16x8*)(dst + (pb + px) * 64 + cho) = *(const bf16x8*)(&tile[px * 72 + cho]);
        }
    }
}

// ---------------- K2: flash attention, reg-prefetch pipeline, fused Q/K affine ----------------
// grid 512 = 8 heads x 16 q-blocks(256q) x 4 L-splits; wave owns 64 q.
__global__ __launch_bounds__(256, 2) void k_attn(const bf16* __restrict__ qkvT,
                                                 const float2* __restrict__ cs,
                                                 const float* __restrict__ gnw,
                                                 const float* __restrict__ gnb,
                                                 bf16* __restrict__ Opart,
                                                 float* __restrict__ Lsum) {
    int bid   = blockIdx.x;
    int h     = bid & 7;                  // XCD L2 affinity
    int qb    = (bid >> 3) & 15;
    int split = bid >> 7;                 // 0..3
    int wid = threadIdx.x >> 6, lane = threadIdx.x & 63;
    int quad = lane >> 4, l15 = lane & 15;
    const bf16* QT = qkvT + h * 786432;
    const bf16* KT = QT + 262144;
    const bf16* V  = QT + 524288;
    int qw = qb * 256 + wid * 64;

    __shared__ __attribute__((aligned(16))) bf16 Ks[64 * 72];
    __shared__ __attribute__((aligned(16))) bf16 Vs[64 * 72];
    __shared__ __attribute__((aligned(16))) bf16 Ps[4][64 * 72];

    // ---- inline group stats for Q (g=h*3+1) and K (g=h*3+0) ----
    float2 vq = cs[(h * 3 + 1) * 64 + lane];
    float2 vk = cs[(h * 3 + 0) * 64 + lane];
    float sq = vq.x, ssq = vq.y, sk = vk.x, ssk = vk.y;
#pragma unroll
    for (int m = 1; m < 64; m <<= 1) {
        sq += __shfl_xor(sq, m, 64); ssq += __shfl_xor(ssq, m, 64);
        sk += __shfl_xor(sk, m, 64); ssk += __shfl_xor(ssk, m, 64);
    }
    const float N = 262144.0f;
    float mq = sq / N, iq = rsqrtf(ssq / N - mq * mq + 1e-5f);
    float mk = sk / N, ik = rsqrtf(ssk / N - mk * mk + 1e-5f);

    // ---- staging-channel K affine consts (this lane always stages kd in [koff,koff+8)) ----
    int r0   = threadIdx.x >> 3;          // staging rows r0 and r0+32
    int koff = (threadIdx.x & 7) * 8;
    float akc[8], bkc[8];
#pragma unroll
    for (int j = 0; j < 8; j++) {
        float gw = gnw[h * 192 + koff + j];
        akc[j] = ik * gw;
        bkc[j] = gnb[h * 192 + koff + j] - mk * akc[j];
    }

    // ---- Q B-fragments with affine (loop-invariant) ----
    bf16x8 bq[4][2];
#pragma unroll
    for (int ks = 0; ks < 2; ks++) {
        float aqc[8], bqc[8];
#pragma unroll
        for (int j = 0; j < 8; j++) {
            int ch = h * 192 + 64 + ks * 32 + quad * 8 + j;
            float gw = gnw[ch];
            aqc[j] = iq * gw * QF;
            bqc[j] = (gnb[ch] - mq * iq * gw) * QF;
        }
#pragma unroll
        for (int qs = 0; qs < 4; qs++) {
            bf16x8 raw = *(const bf16x8*)(QT + (qw + qs * 16 + l15) * 64 + ks * 32 + quad * 8);
            bf16x8 o;
#pragma unroll
            for (int j = 0; j < 8; j++) o[j] = (bf16)(aqc[j] * (float)raw[j] + bqc[j]);
            bq[qs][ks] = o;
        }
    }

    bf16x8 ones;
#pragma unroll
    for (int j = 0; j < 8; j++) ones[j] = (bf16)1.0f;

    f32x4 oacc[4][4];
#pragma unroll
    for (int c = 0; c < 4; c++)
#pragma unroll
        for (int qs = 0; qs < 4; qs++) oacc[c][qs] = (f32x4){0.f, 0.f, 0.f, 0.f};
    f32x4 oL[4];
#pragma unroll
    for (int qs = 0; qs < 4; qs++) oL[qs] = (f32x4){0.f, 0.f, 0.f, 0.f};

    int t0 = split * 16, t1 = t0 + 16;

    // prefetch tile t0 into registers
    bf16x8 kf0, kf1, vf0, vf1;
    {
        int lb0 = t0 * 64;
        kf0 = *(const bf16x8*)(KT + (lb0 + r0) * 64 + koff);
        kf1 = *(const bf16x8*)(KT + (lb0 + r0 + 32) * 64 + koff);
        vf0 = *(const bf16x8*)(V + r0 * 4096 + lb0 + koff);
        vf1 = *(const bf16x8*)(V + (r0 + 32) * 4096 + lb0 + koff);
    }

    for (int lt = t0; lt < t1; lt++) {
        __syncthreads();                  // prev-tile consumers done
        // stage prefetched regs -> LDS (K gets affine here)
        {
            bf16x8 k0, k1;
#pragma unroll
            for (int j = 0; j < 8; j++) {
                k0[j] = (bf16)(akc[j] * (float)kf0[j] + bkc[j]);
                k1[j] = (bf16)(akc[j] * (float)kf1[j] + bkc[j]);
            }
            *(bf16x8*)(Ks + r0 * 72 + koff)        = k0;
            *(bf16x8*)(Ks + (r0 + 32) * 72 + koff) = k1;
            *(bf16x8*)(Vs + r0 * 72 + koff)        = vf0;
            *(bf16x8*)(Vs + (r0 + 32) * 72 + koff) = vf1;
        }
        __syncthreads();                  // staging visible

        // prefetch NEXT tile (latency overlaps the compute below)
        if (lt + 1 < t1) {
            int nb = (lt + 1) * 64;
            kf0 = *(const bf16x8*)(KT + (nb + r0) * 64 + koff);
            kf1 = *(const bf16x8*)(KT + (nb + r0 + 32) * 64 + koff);
            vf0 = *(const bf16x8*)(V + r0 * 4096 + nb + koff);
            vf1 = *(const bf16x8*)(V + (r0 + 32) * 4096 + nb + koff);
        }

        // K / V fragments (reused across 4 q-subtiles)
        bf16x8 ak[2][4];
#pragma unroll
        for (int ks = 0; ks < 2; ks++)
#pragma unroll
            for (int lb = 0; lb < 4; lb++)
                ak[ks][lb] = *(const bf16x8*)(Ks + (lb * 16 + l15) * 72 + ks * 32 + quad * 8);
        bf16x8 av[2][4];
#pragma unroll
        for (int ks = 0; ks < 2; ks++)
#pragma unroll
            for (int c = 0; c < 4; c++)
                av[ks][c] = *(const bf16x8*)(Vs + (c * 16 + l15) * 72 + ks * 32 + quad * 8);

#pragma unroll
        for (int qs = 0; qs < 4; qs++) {
            // S^T = K·Q
            f32x4 s[4];
#pragma unroll
            for (int lb = 0; lb < 4; lb++) s[lb] = (f32x4){0.f, 0.f, 0.f, 0.f};
#pragma unroll
            for (int ks = 0; ks < 2; ks++)
#pragma unroll
                for (int lb = 0; lb < 4; lb++)
                    s[lb] = __builtin_amdgcn_mfma_f32_16x16x32_bf16(ak[ks][lb], bq[qs][ks], s[lb], 0, 0, 0);
            // P = exp2(S^T) -> Ps[q][l] (per-wave private, no barrier)
#pragma unroll
            for (int lb = 0; lb < 4; lb++) {
                bf16x4 pk;
                pk[0] = (bf16)__builtin_amdgcn_exp2f(s[lb][0]);
                pk[1] = (bf16)__builtin_amdgcn_exp2f(s[lb][1]);
                pk[2] = (bf16)__builtin_amdgcn_exp2f(s[lb][2]);
                pk[3] = (bf16)__builtin_amdgcn_exp2f(s[lb][3]);
                *(bf16x4*)(&Ps[wid][(qs * 16 + l15) * 72 + lb * 16 + quad * 4]) = pk;
            }
            // O += V·P, L += 1·P (denominator via MFMA)
            bf16x8 bp0 = *(const bf16x8*)(&Ps[wid][(qs * 16 + l15) * 72 + quad * 8]);
            bf16x8 bp1 = *(const bf16x8*)(&Ps[wid][(qs * 16 + l15) * 72 + 32 + quad * 8]);
            oL[qs] = __builtin_amdgcn_mfma_f32_16x16x32_bf16(ones, bp0, oL[qs], 0, 0, 0);
            oL[qs] = __builtin_amdgcn_mfma_f32_16x16x32_bf16(ones, bp1, oL[qs], 0, 0, 0);
#pragma unroll
            for (int c = 0; c < 4; c++) {
                oacc[c][qs] = __builtin_amdgcn_mfma_f32_16x16x32_bf16(av[0][c], bp0, oacc[c][qs], 0, 0, 0);
                oacc[c][qs] = __builtin_amdgcn_mfma_f32_16x16x32_bf16(av[1][c], bp1, oacc[c][qs], 0, 0, 0);
            }
        }
    }

    // L: every lane of quad 0 already holds L[q=qs*16+l15] in oL[qs][0]
    if (quad == 0)
#pragma unroll
        for (int qs = 0; qs < 4; qs++)
            Lsum[split * 32768 + h * 4096 + qw + qs * 16 + l15] = oL[qs][0];

    bf16* Ob = Opart + split * 2097152;
#pragma unroll
    for (int c = 0; c < 4; c++)
#pragma unroll
        for (int qs = 0; qs < 4; qs++)
#pragma unroll
            for (int r = 0; r < 4; r++)
                Ob[(h * 64 + c * 16 + quad * 4 + r) * 4096 + qw + qs * 16 + l15] = (bf16)oacc[c][qs][r];
}

// ---------------- K3: combine 4 splits + V affine (stats inline) + normalize ----------------
__global__ void k_final(const bf16* __restrict__ Opart, const float* __restrict__ Lsum,
                        const float2* __restrict__ cs, const float* __restrict__ gnw,
                        const float* __restrict__ gnb, float* __restrict__ out) {
    int gid = blockIdx.x * 256 + threadIdx.x;    // 262144
    int row = gid >> 9;
    int c8  = (gid & 511) << 3;
    int h   = row >> 6;

    int g = h * 3 + 2;
    int c = threadIdx.x & 63;
    float2 v = cs[g * 64 + c];
    float s = v.x, ss = v.y;
#pragma unroll
    for (int m = 1; m < 64; m <<= 1) { s += __shfl_xor(s, m, 64); ss += __shfl_xor(ss, m, 64); }
    const float N = 262144.0f;
    float mean = s / N;
    float inv  = rsqrtf(ss / N - mean * mean + 1e-5f);
    int gi = h * 192 + 128 + (row & 63);
    float gw = gnw[gi];
    float va = inv * gw;
    float vb = gnb[gi] - mean * inv * gw;

    float o[8] = {0, 0, 0, 0, 0, 0, 0, 0};
    float l[8] = {0, 0, 0, 0, 0, 0, 0, 0};
#pragma unroll
    for (int sp = 0; sp < 4; sp++) {
        bf16x8 vv = *(const bf16x8*)(Opart + sp * 2097152 + row * 4096 + c8);
        const float* L = Lsum + sp * 32768 + h * 4096 + c8;
        float4 l0 = *(const float4*)L;
        float4 l1 = *(const float4*)(L + 4);
#pragma unroll
        for (int j = 0; j < 8; j++) o[j] += (float)vv[j];
        l[0] += l0.x; l[1] += l0.y; l[2] += l0.z; l[3] += l0.w;
        l[4] += l1.x; l[5] += l1.y; l[6] += l1.z; l[7] += l1.w;
    }
    float4 r0, r1;
    r0.x = va * o[0] / l[0] + vb; r0.y = va * o[1] / l[1] + vb;
    r0.z = va * o[2] / l[2] + vb; r0.w = va * o[3] / l[3] + vb;
    r1.x = va * o[4] / l[4] + vb; r1.y = va * o[5] / l[5] + vb;
    r1.z = va * o[6] / l[6] + vb; r1.w = va * o[7] / l[7] + vb;
    *(float4*)(out + row * 4096 + c8)     = r0;
    *(float4*)(out + row * 4096 + c8 + 4) = r1;
}

extern "C" void kernel_launch(void* const* d_in, const int* in_sizes, int n_in,
                              void* d_out, int out_size, void* d_ws, size_t ws_size,
                              hipStream_t stream) {
    const float* x      = (const float*)d_in[0];
    const float* conv_w = (const float*)d_in[1];
    const float* gn_w   = (const float*)d_in[2];
    const float* gn_b   = (const float*)d_in[3];
    float* out = (float*)d_out;
    char* ws = (char*)d_ws;

    // qkvT [0,12582912); Opart 4x4MB [12582912,29360128); Wb/xT alias Opart
    // (dead after k_conv; Opart first written by k_attn).
    bf16*   qkvT  = (bf16*) (ws);
    bf16*   Opart = (bf16*) (ws + 12582912);
    bf16*   Wb    = (bf16*) (ws + 12582912);
    bf16*   xT    = (bf16*) (ws + 13369344);
    float*  Lsum  = (float*)(ws + 29360128);        // 4*131072 B
    float*  cs    = (float*)(ws + 29884416);        // 12288 B

    hipLaunchKernelGGL(k_misc,  dim3(897),  dim3(256), 0, stream, x, conv_w, xT, Wb, cs);
    hipLaunchKernelGGL(k_conv,  dim3(1536), dim3(256), 0, stream, Wb, xT, qkvT, cs);
    hipLaunchKernelGGL(k_attn,  dim3(512),  dim3(256), 0, stream, qkvT, (const float2*)cs, gn_w, gn_b, Opart, Lsum);
    hipLaunchKernelGGL(k_final, dim3(1024), dim3(256), 0, stream, Opart, Lsum, (const float2*)cs, gn_w, gn_b, out);
}